// Round 10
// baseline (16153.444 us; speedup 1.0000x reference)
//
#include <hip/hip_runtime.h>
#include <stdint.h>
#include <math.h>

#define NB 1024      // batch
#define NH 256       // hidden
#define NG 1024      // 4*NH gate rows
#define NLOOK 336    // encoder steps
#define NHOR 168     // decoder steps
#define TPB 256
#define PLANE (NG * NH)   // 262144 elems per bf16 weight plane

// ---------- bf16 helpers (RNE) ----------
__device__ __forceinline__ unsigned short bf16_rne(float f) {
  union { float f; uint32_t u; } v; v.f = f;
  uint32_t u = v.u;
  u += 0x7FFFu + ((u >> 16) & 1u);
  return (unsigned short)(u >> 16);
}
__device__ __forceinline__ float bf16_f(unsigned short h) {
  union { uint32_t u; float f; } v; v.u = ((uint32_t)h) << 16;
  return v.f;
}
__device__ __forceinline__ float sigm(float x) {
  return __builtin_amdgcn_rcpf(1.0f + __expf(-x));
}
__device__ __forceinline__ float tanh_(float x) {
  return 1.0f - 2.0f * __builtin_amdgcn_rcpf(1.0f + __expf(2.0f * x));
}
__device__ __forceinline__ uint32_t pack_h(float hv) {
  const unsigned short hb = bf16_rne(hv);
  const unsigned short lb = bf16_rne(hv - bf16_f(hb));
  return ((uint32_t)hb << 16) | (uint32_t)lb;
}

typedef short bf16x8 __attribute__((ext_vector_type(8)));
typedef float f32x4 __attribute__((ext_vector_type(4)));
typedef uint32_t u32v4 __attribute__((ext_vector_type(4)));

// ---------- weight split prologue ----------
__global__ __launch_bounds__(TPB) void split_w(const float* __restrict__ W,
                                               unsigned short* __restrict__ hi,
                                               unsigned short* __restrict__ lo) {
  const int idx = blockIdx.x * TPB + threadIdx.x;
  const float w = W[idx];
  const unsigned short h = bf16_rne(w);
  hi[idx] = h;
  lo[idx] = bf16_rne(w - bf16_f(h));
}

__device__ __forceinline__ void wait_vm0() {
  asm volatile("s_waitcnt vmcnt(0)" ::: "memory");
  __builtin_amdgcn_sched_barrier(0);
}

// ---------- A-fragment plane ----------
struct APlane { u32v4 q[16]; };

__device__ __forceinline__ void aplane_issue(APlane& A, const uint32_t* __restrict__ hp,
                                             int row, int lg, bool fast) {
  const uint32_t* ap = hp + (size_t)row * NH;
  if (fast) {
#pragma unroll
    for (int kt = 0; kt < 8; ++kt) {
      const uint32_t* p0 = ap + kt * 32 + lg * 8;
      asm volatile("global_load_dwordx4 %0, %1, off sc0" : "=v"(A.q[2 * kt]) : "v"(p0));
      asm volatile("global_load_dwordx4 %0, %1, off sc0" : "=v"(A.q[2 * kt + 1]) : "v"(p0 + 4));
    }
  } else {
#pragma unroll
    for (int kt = 0; kt < 8; ++kt) {
      const uint32_t* p0 = ap + kt * 32 + lg * 8;
      asm volatile("global_load_dwordx4 %0, %1, off sc0 sc1" : "=v"(A.q[2 * kt]) : "v"(p0));
      asm volatile("global_load_dwordx4 %0, %1, off sc0 sc1" : "=v"(A.q[2 * kt + 1]) : "v"(p0 + 4));
    }
  }
}

// ---------- GEMM fragment (proven rounds 4-8) ----------
__device__ __forceinline__ void gemm_frag(f32x4 acc[4], const APlane& A,
                                          const unsigned short* __restrict__ whi,
                                          const unsigned short* __restrict__ wlo,
                                          int h0off, int lg, int ln16) {
  const unsigned short* bh0 = whi + (size_t)(h0off + ln16) * NH;
  const unsigned short* bl0 = wlo + (size_t)(h0off + ln16) * NH;
#pragma unroll
  for (int kt = 0; kt < 8; ++kt) {
    bf16x8 Ah, Al;
#pragma unroll
    for (int half = 0; half < 2; ++half)
#pragma unroll
      for (int j = 0; j < 4; ++j) {
        const uint32_t w = A.q[2 * kt + half][j];
        Ah[half * 4 + j] = (short)(w >> 16);
        Al[half * 4 + j] = (short)(w & 0xFFFFu);
      }
    const int ko = kt * 32 + lg * 8;
#pragma unroll
    for (int g = 0; g < 4; ++g) {
      const bf16x8 Bh = *(const bf16x8*)(bh0 + (size_t)g * (NH * NH) + ko);
      const bf16x8 Bl = *(const bf16x8*)(bl0 + (size_t)g * (NH * NH) + ko);
      acc[g] = __builtin_amdgcn_mfma_f32_16x16x32_bf16(Ah, Bh, acc[g], 0, 0, 0);
      acc[g] = __builtin_amdgcn_mfma_f32_16x16x32_bf16(Ah, Bl, acc[g], 0, 0, 0);
      acc[g] = __builtin_amdgcn_mfma_f32_16x16x32_bf16(Al, Bh, acc[g], 0, 0, 0);
    }
  }
}

// ---------- h-tile store via LDS transpose ----------
__device__ __forceinline__ void store_htile(uint32_t* __restrict__ hplane,
                                            const uint32_t pk[4],
                                            uint32_t (*tr)[65],
                                            int b0, int h0off, int tx,
                                            int wv, int lg, int ln16, bool fast) {
  __syncthreads();
#pragma unroll
  for (int r = 0; r < 4; ++r) tr[ln16][wv * 16 + lg * 4 + r] = pk[r];
  __syncthreads();
  const int ri = tx >> 2, c0 = (tx & 3) * 4;
  u32v4 v;
  v[0] = tr[c0 + 0][ri]; v[1] = tr[c0 + 1][ri];
  v[2] = tr[c0 + 2][ri]; v[3] = tr[c0 + 3][ri];
  uint32_t* dst = hplane + (size_t)(b0 + ri) * NH + h0off + c0;
  if (fast) {
    *(u32v4*)dst = v;   // write-through L1 -> local L2
  } else {
    asm volatile("global_store_dwordx4 %0, %1, off sc0 sc1" :: "v"(dst), "v"(v) : "memory");
  }
}

// ---------- group barrier: proven round-7/8 mechanism (agent scope, relaxed poll) ----------
__device__ __forceinline__ void barrier_arrive(unsigned* line, unsigned* bno, int tx) {
  asm volatile("s_waitcnt vmcnt(0)" ::: "memory");   // all h/partial stores completed
  __syncthreads();
  if (tx == 0)
    __hip_atomic_fetch_add(line, 1u, __ATOMIC_RELAXED, __HIP_MEMORY_SCOPE_AGENT);
  ++(*bno);
}
__device__ __forceinline__ void barrier_wait(unsigned* line, unsigned bno, int tx) {
  if (tx == 0) {
    while (__hip_atomic_load(line, __ATOMIC_RELAXED, __HIP_MEMORY_SCOPE_AGENT) <
           16u * bno)
      __builtin_amdgcn_s_sleep(1);
  }
  __syncthreads();
  asm volatile("" ::: "memory");
}

// ---------- the whole network in one launch ----------
__global__ __launch_bounds__(TPB, 1) void lstm_persist(
    const float* __restrict__ x,
    const float* __restrict__ eWih0, const float* __restrict__ eb0,
    const float* __restrict__ eb1,
    const float* __restrict__ dWih0, const float* __restrict__ db0,
    const float* __restrict__ db1,
    const float* __restrict__ fcW, const float* __restrict__ fcb,
    const unsigned short* __restrict__ wp,
    uint32_t* __restrict__ hbase,
    unsigned* __restrict__ ctr,       // 16 groups x 32 u32 (main barrier lines)
    int* __restrict__ xcds,           // [256]
    unsigned* __restrict__ boot,      // 16 groups x 32 u32 (bootstrap lines)
    float* __restrict__ predp,        // [2][16][NB] fc partials
    float* __restrict__ out) {
  __shared__ uint32_t tr[16][65];
  __shared__ int s_fast;
  const int tx = threadIdx.x, bx = blockIdx.x;
  const int bt = bx & 15, ht = bx >> 4;   // group members {bt+16k}: bx%8==bt%8 -> same XCD under round-robin
  const int b0 = bt * 64, h0off = ht * 16;
  const int wv = tx >> 6, l = tx & 63, lg = l >> 4, ln16 = l & 15;
  const int hcol = h0off + ln16;
  const int arow = b0 + wv * 16 + ln16;
  unsigned* ctr_line = &ctr[bt * 32];
  unsigned* boot_line = &boot[bt * 32];

  // ---- one-time group-local placement detection (proven barrier mechanism) ----
  int xcc;
  asm volatile("s_getreg_b32 %0, hwreg(HW_REG_XCC_ID)" : "=s"(xcc));
  if (tx == 0) {
    int* p = &xcds[bx];
    asm volatile("global_store_dword %0, %1, off sc0 sc1" :: "v"(p), "v"(xcc) : "memory");
    asm volatile("s_waitcnt vmcnt(0)" ::: "memory");
    __hip_atomic_fetch_add(boot_line, 1u, __ATOMIC_RELAXED, __HIP_MEMORY_SCOPE_AGENT);
    while (__hip_atomic_load(boot_line, __ATOMIC_RELAXED, __HIP_MEMORY_SCOPE_AGENT) < 16u)
      __builtin_amdgcn_s_sleep(1);
  }
  __syncthreads();
  int okv = 1;
  if (tx < 16) {
    const int* p = &xcds[bt + 16 * tx];
    int v;
    asm volatile("global_load_dword %0, %1, off sc0 sc1\n\ts_waitcnt vmcnt(0)"
                 : "=v"(v) : "v"(p));
    okv = (v == xcc) ? 1 : 0;
  }
  const bool wave_ok = __all(okv != 0);
  if (tx == 0) s_fast = wave_ok ? 1 : 0;
  __syncthreads();
  const bool fast = (s_fast != 0);

  const unsigned short* W_eWhh0_hi = wp + 0 * 2 * PLANE;
  const unsigned short* W_eWhh0_lo = W_eWhh0_hi + PLANE;
  const unsigned short* W_eWih1_hi = wp + 1 * 2 * PLANE;
  const unsigned short* W_eWih1_lo = W_eWih1_hi + PLANE;
  const unsigned short* W_eWhh1_hi = wp + 2 * 2 * PLANE;
  const unsigned short* W_eWhh1_lo = W_eWhh1_hi + PLANE;
  const unsigned short* W_dWhh0_hi = wp + 3 * 2 * PLANE;
  const unsigned short* W_dWhh0_lo = W_dWhh0_hi + PLANE;
  const unsigned short* W_dWih1_hi = wp + 4 * 2 * PLANE;
  const unsigned short* W_dWih1_lo = W_dWih1_hi + PLANE;
  const unsigned short* W_dWhh1_hi = wp + 5 * 2 * PLANE;
  const unsigned short* W_dWhh1_lo = W_dWhh1_hi + PLANE;

  const int HP = NB * NH;
  uint32_t* h0c = hbase + 0 * HP; uint32_t* h0n = hbase + 1 * HP;
  uint32_t* h1c = hbase + 2 * HP; uint32_t* h1n = hbase + 3 * HP;

  float ewv[4], eb0v[4], eb1v[4], dwv[4], db0v[4], db1v[4];
#pragma unroll
  for (int g = 0; g < 4; ++g) {
    ewv[g]  = eWih0[g * NH + hcol];
    eb0v[g] = eb0[g * NH + hcol];
    eb1v[g] = eb1[g * NH + hcol];
    dwv[g]  = dWih0[g * NH + hcol];
    db0v[g] = db0[g * NH + hcol];
    db1v[g] = db1[g * NH + hcol];
  }
  const float fcwv = fcW[hcol];
  const float fcbv = fcb[0];

  float c0r[4] = {0.f, 0.f, 0.f, 0.f};
  float c1r[4] = {0.f, 0.f, 0.f, 0.f};
  unsigned bno = 0;

  // ---- interval 0: layer0(0) ----
  {
    uint32_t pk[4];
#pragma unroll
    for (int r = 0; r < 4; ++r) {
      const int b = b0 + wv * 16 + lg * 4 + r;
      const float pv = x[b * NLOOK + 0];
      const float ig = sigm(pv * ewv[0] + eb0v[0]);
      const float fg = sigm(pv * ewv[1] + eb0v[1]);
      const float gg = tanh_(pv * ewv[2] + eb0v[2]);
      const float og = sigm(pv * ewv[3] + eb0v[3]);
      c0r[r] = fg * c0r[r] + ig * gg;
      pk[r] = pack_h(og * tanh_(c0r[r]));
    }
    store_htile(h0n, pk, tr, b0, h0off, tx, wv, lg, ln16, fast);
    barrier_arrive(ctr_line, &bno, tx);
    { uint32_t* s0 = h0c; h0c = h0n; h0n = s0; }
  }

  // ---- fused encoder intervals s=1..336: layer1(s-1) + layer0(s) ----
  // A0 and A1 both loaded POST-wait (fixes rounds-7/8 latent pre-wait race on h1).
  for (int s = 1; s <= NLOOK; ++s) {
    float xv[4];
    if (s <= NLOOK - 1) {
#pragma unroll
      for (int r = 0; r < 4; ++r)
        xv[r] = x[(b0 + wv * 16 + lg * 4 + r) * NLOOK + s];
    }
    barrier_wait(ctr_line, bno, tx);   // h0(s-1), h1(s-2) published

    APlane A0, A1;
    aplane_issue(A0, h0c, arow, lg, fast);
    if (s >= 2) aplane_issue(A1, h1c, arow, lg, fast);
    wait_vm0();

    f32x4 acc1[4] = {};
    gemm_frag(acc1, A0, W_eWih1_hi, W_eWih1_lo, h0off, lg, ln16);
    if (s >= 2) gemm_frag(acc1, A1, W_eWhh1_hi, W_eWhh1_lo, h0off, lg, ln16);
    uint32_t pk1[4];
#pragma unroll
    for (int r = 0; r < 4; ++r) {
      const float ig = sigm(acc1[0][r] + eb1v[0]);
      const float fg = sigm(acc1[1][r] + eb1v[1]);
      const float gg = tanh_(acc1[2][r] + eb1v[2]);
      const float og = sigm(acc1[3][r] + eb1v[3]);
      c1r[r] = fg * c1r[r] + ig * gg;
      pk1[r] = pack_h(og * tanh_(c1r[r]));
    }
    store_htile(h1n, pk1, tr, b0, h0off, tx, wv, lg, ln16, fast);

    if (s <= NLOOK - 1) {
      f32x4 acc0[4] = {};
      gemm_frag(acc0, A0, W_eWhh0_hi, W_eWhh0_lo, h0off, lg, ln16);
      uint32_t pk0[4];
#pragma unroll
      for (int r = 0; r < 4; ++r) {
        const float ig = sigm(acc0[0][r] + xv[r] * ewv[0] + eb0v[0]);
        const float fg = sigm(acc0[1][r] + xv[r] * ewv[1] + eb0v[1]);
        const float gg = tanh_(acc0[2][r] + xv[r] * ewv[2] + eb0v[2]);
        const float og = sigm(acc0[3][r] + xv[r] * ewv[3] + eb0v[3]);
        c0r[r] = fg * c0r[r] + ig * gg;
        pk0[r] = pack_h(og * tanh_(c0r[r]));
      }
      store_htile(h0n, pk0, tr, b0, h0off, tx, wv, lg, ln16, fast);
    }
    barrier_arrive(ctr_line, &bno, tx);
    if (s <= NLOOK - 1) { uint32_t* s0 = h0c; h0c = h0n; h0n = s0; }
    { uint32_t* s0 = h1c; h1c = h1n; h1n = s0; }
  }

  // ---- decoder: 2 intervals per step (pre-wait loads here are barrier-covered) ----
  for (int t = 0; t < NHOR; ++t) {
    // d0: layer0(t) — h0(t-1) covered by d1(t-1)'s wait (encoder-final wait for t=0)
    {
      APlane A0;
      aplane_issue(A0, h0c, arow, lg, fast);
      float pvx[4];
      if (t == 0) {
#pragma unroll
        for (int r = 0; r < 4; ++r)
          pvx[r] = x[(b0 + wv * 16 + lg * 4 + r) * NLOOK + (NLOOK - 1)];
      }
      wait_vm0();
      f32x4 acc0[4] = {};
      gemm_frag(acc0, A0, W_dWhh0_hi, W_dWhh0_lo, h0off, lg, ln16);
      barrier_wait(ctr_line, bno, tx);   // partials(t-1) published

      float pv[4];
      if (t == 0) {
#pragma unroll
        for (int r = 0; r < 4; ++r) pv[r] = pvx[r];
      } else {
        const float* src = predp + (size_t)((t - 1) & 1) * 16 * NB + ln16 * NB
                           + b0 + wv * 16 + lg * 4;
        f32x4 pp;
        if (fast) {
          asm volatile("global_load_dwordx4 %0, %1, off sc0" : "=v"(pp) : "v"(src));
        } else {
          asm volatile("global_load_dwordx4 %0, %1, off sc0 sc1" : "=v"(pp) : "v"(src));
        }
        wait_vm0();
#pragma unroll
        for (int m = 1; m < 16; m <<= 1) {
#pragma unroll
          for (int r = 0; r < 4; ++r) pp[r] += __shfl_xor(pp[r], m, 64);
        }
#pragma unroll
        for (int r = 0; r < 4; ++r) pv[r] = pp[r] + fcbv;
      }
      uint32_t pk0[4];
#pragma unroll
      for (int r = 0; r < 4; ++r) {
        const float ig = sigm(acc0[0][r] + pv[r] * dwv[0] + db0v[0]);
        const float fg = sigm(acc0[1][r] + pv[r] * dwv[1] + db0v[1]);
        const float gg = tanh_(acc0[2][r] + pv[r] * dwv[2] + db0v[2]);
        const float og = sigm(acc0[3][r] + pv[r] * dwv[3] + db0v[3]);
        c0r[r] = fg * c0r[r] + ig * gg;
        pk0[r] = pack_h(og * tanh_(c0r[r]));
      }
      store_htile(h0n, pk0, tr, b0, h0off, tx, wv, lg, ln16, fast);
      if (ht == 0 && t >= 1 && ln16 == 0) {
#pragma unroll
        for (int r = 0; r < 4; ++r) {
          const int b = b0 + wv * 16 + lg * 4 + r;
          out[b * NHOR + (t - 1)] = pv[r];
        }
      }
      barrier_arrive(ctr_line, &bno, tx);
      { uint32_t* s0 = h0c; h0c = h0n; h0n = s0; }
    }

    // d1: layer1(t) + fc partial — h1(t-1) covered by d0(t)'s wait
    {
      APlane A1;
      aplane_issue(A1, h1c, arow, lg, fast);
      wait_vm0();
      f32x4 acc1[4] = {};
      gemm_frag(acc1, A1, W_dWhh1_hi, W_dWhh1_lo, h0off, lg, ln16);
      barrier_wait(ctr_line, bno, tx);   // h0(t) published

      APlane A0;
      aplane_issue(A0, h0c, arow, lg, fast);
      wait_vm0();
      gemm_frag(acc1, A0, W_dWih1_hi, W_dWih1_lo, h0off, lg, ln16);
      float hvr[4];
      uint32_t pk1[4];
#pragma unroll
      for (int r = 0; r < 4; ++r) {
        const float ig = sigm(acc1[0][r] + db1v[0]);
        const float fg = sigm(acc1[1][r] + db1v[1]);
        const float gg = tanh_(acc1[2][r] + db1v[2]);
        const float og = sigm(acc1[3][r] + db1v[3]);
        c1r[r] = fg * c1r[r] + ig * gg;
        hvr[r] = og * tanh_(c1r[r]);
        pk1[r] = pack_h(hvr[r]);
      }
      store_htile(h1n, pk1, tr, b0, h0off, tx, wv, lg, ln16, fast);

      float s4[4];
#pragma unroll
      for (int r = 0; r < 4; ++r) s4[r] = hvr[r] * fcwv;
#pragma unroll
      for (int m = 1; m < 16; m <<= 1) {
#pragma unroll
        for (int r = 0; r < 4; ++r) s4[r] += __shfl_xor(s4[r], m, 64);
      }
      if (ln16 == 0) {
        float* dst = predp + (size_t)(t & 1) * 16 * NB + ht * NB + b0 + wv * 16 + lg * 4;
        f32x4 v; v[0] = s4[0]; v[1] = s4[1]; v[2] = s4[2]; v[3] = s4[3];
        if (fast) {
          *(f32x4*)dst = v;
        } else {
          asm volatile("global_store_dwordx4 %0, %1, off sc0 sc1" :: "v"(dst), "v"(v) : "memory");
        }
      }
      barrier_arrive(ctr_line, &bno, tx);
      { uint32_t* s0 = h1c; h1c = h1n; h1n = s0; }
    }
  }

  // ---- tail: final prediction column ----
  barrier_wait(ctr_line, bno, tx);
  if (ht == 0) {
    const float* src = predp + (size_t)((NHOR - 1) & 1) * 16 * NB + ln16 * NB
                       + b0 + wv * 16 + lg * 4;
    f32x4 pp;
    if (fast) {
      asm volatile("global_load_dwordx4 %0, %1, off sc0" : "=v"(pp) : "v"(src));
    } else {
      asm volatile("global_load_dwordx4 %0, %1, off sc0 sc1" : "=v"(pp) : "v"(src));
    }
    wait_vm0();
#pragma unroll
    for (int m = 1; m < 16; m <<= 1) {
#pragma unroll
      for (int r = 0; r < 4; ++r) pp[r] += __shfl_xor(pp[r], m, 64);
    }
    if (ln16 == 0) {
#pragma unroll
      for (int r = 0; r < 4; ++r) {
        const int b = b0 + wv * 16 + lg * 4 + r;
        out[b * NHOR + (NHOR - 1)] = pp[r] + fcbv;
      }
    }
  }
}

extern "C" void kernel_launch(void* const* d_in, const int* in_sizes, int n_in,
                              void* d_out, int out_size, void* d_ws, size_t ws_size,
                              hipStream_t stream) {
  (void)in_sizes; (void)n_in; (void)out_size; (void)ws_size;
  const float* x     = (const float*)d_in[0];
  const float* eWih0 = (const float*)d_in[1];
  const float* eWhh0 = (const float*)d_in[2];
  const float* eb0   = (const float*)d_in[3];
  const float* eWih1 = (const float*)d_in[4];
  const float* eWhh1 = (const float*)d_in[5];
  const float* eb1   = (const float*)d_in[6];
  const float* dWih0 = (const float*)d_in[7];
  const float* dWhh0 = (const float*)d_in[8];
  const float* db0   = (const float*)d_in[9];
  const float* dWih1 = (const float*)d_in[10];
  const float* dWhh1 = (const float*)d_in[11];
  const float* db1   = (const float*)d_in[12];
  const float* fcW   = (const float*)d_in[13];
  const float* fcb   = (const float*)d_in[14];
  float* out = (float*)d_out;

  uint8_t* wsb = (uint8_t*)d_ws;
  unsigned* ctr = (unsigned*)wsb;                              // [0,2048): 16 x 128B barrier lines
  int* xcds = (int*)(wsb + 4096);                              // [4096,5120)
  unsigned* boot = (unsigned*)(wsb + 8192);                    // [8192,10240): bootstrap lines
  float* predp = (float*)(wsb + 16384);                        // 2*16*NB*4 = 128KB
  unsigned short* wp = (unsigned short*)(wsb + 1048576);       // 12 planes = 6 MiB
  uint32_t* hbase = (uint32_t*)(wsb + 1048576 + (size_t)12 * PLANE * 2);  // 4 MiB

  hipMemsetAsync(d_ws, 0, 16384, stream);  // ctr + xcds + boot

  const float* Wsrc[6] = { eWhh0, eWih1, eWhh1, dWhh0, dWih1, dWhh1 };
  for (int m = 0; m < 6; ++m)
    split_w<<<dim3(PLANE / TPB), dim3(TPB), 0, stream>>>(
        Wsrc[m], wp + (size_t)m * 2 * PLANE, wp + (size_t)m * 2 * PLANE + PLANE);

  lstm_persist<<<dim3(256), dim3(TPB), 0, stream>>>(
      x, eWih0, eb0, eb1, dWih0, db0, db1, fcW, fcb,
      wp, hbase, ctr, xcds, boot, predp, out);
}

// Round 13
// 14649.744 us; speedup vs baseline: 1.1026x; 1.1026x over previous
//
#include <hip/hip_runtime.h>
#include <stdint.h>
#include <math.h>

#define NB 1024      // batch
#define NH 256       // hidden
#define NG 1024      // 4*NH gate rows
#define NLOOK 336    // encoder steps
#define NHOR 168     // decoder steps
#define TPB 256
#define PLANE (NG * NH)   // 262144 elems per bf16 weight plane

// ---------- bf16 helpers (RNE) ----------
__device__ __forceinline__ unsigned short bf16_rne(float f) {
  union { float f; uint32_t u; } v; v.f = f;
  uint32_t u = v.u;
  u += 0x7FFFu + ((u >> 16) & 1u);
  return (unsigned short)(u >> 16);
}
__device__ __forceinline__ float bf16_f(unsigned short h) {
  union { uint32_t u; float f; } v; v.u = ((uint32_t)h) << 16;
  return v.f;
}
// fast sigmoid/tanh on hw trans pipes (~1e-7 rel err; bf16 split err dominates)
__device__ __forceinline__ float sigm(float x) {
  return __builtin_amdgcn_rcpf(1.0f + __expf(-x));
}
__device__ __forceinline__ float tanh_(float x) {
  return 1.0f - 2.0f * __builtin_amdgcn_rcpf(1.0f + __expf(2.0f * x));
}
// pack h as (hi<<16)|lo where hi=bf16(h), lo=bf16(h - hi)
__device__ __forceinline__ uint32_t pack_h(float hv) {
  const unsigned short hb = bf16_rne(hv);
  const unsigned short lb = bf16_rne(hv - bf16_f(hb));
  return ((uint32_t)hb << 16) | (uint32_t)lb;
}

typedef short bf16x8 __attribute__((ext_vector_type(8)));
typedef float f32x4 __attribute__((ext_vector_type(4)));
typedef uint32_t u32v4 __attribute__((ext_vector_type(4)));

// ---------- weight split prologue: W(fp32) -> hi/lo bf16 planes ----------
__global__ __launch_bounds__(TPB) void split_w(const float* __restrict__ W,
                                               unsigned short* __restrict__ hi,
                                               unsigned short* __restrict__ lo) {
  const int idx = blockIdx.x * TPB + threadIdx.x;
  const float w = W[idx];
  const unsigned short h = bf16_rne(w);
  hi[idx] = h;
  lo[idx] = bf16_rne(w - bf16_f(h));
}

// ---------- wide device-coherent (cross-XCD fresh) loads/stores ----------
__device__ __forceinline__ void wait_vm0() {
  asm volatile("s_waitcnt vmcnt(0)" ::: "memory");
  __builtin_amdgcn_sched_barrier(0);   // rule #18: no use may hoist above this
}

// ---------- A-fragment plane (16 x 16B coherent loads, issue-only) ----------
struct APlane { u32v4 q[16]; };

__device__ __forceinline__ void aplane_issue(APlane& A, const uint32_t* __restrict__ hp,
                                             int row, int lg) {
  const uint32_t* ap = hp + (size_t)row * NH;
#pragma unroll
  for (int kt = 0; kt < 8; ++kt) {
    const uint32_t* p0 = ap + kt * 32 + lg * 8;
    asm volatile("global_load_dwordx4 %0, %1, off sc0 sc1"
                 : "=v"(A.q[2 * kt]) : "v"(p0));
    asm volatile("global_load_dwordx4 %0, %1, off sc0 sc1"
                 : "=v"(A.q[2 * kt + 1]) : "v"(p0 + 4));
  }
}

// acc[g] += A(16 rows) @ W(gate rows at h0off)^T, 3-term hi/lo split.
// Fragment mapping proven in rounds 4-10 (absmax <= 2.44e-4).
__device__ __forceinline__ void gemm_frag(f32x4 acc[4], const APlane& A,
                                          const unsigned short* __restrict__ whi,
                                          const unsigned short* __restrict__ wlo,
                                          int h0off, int lg, int ln16) {
  const unsigned short* bh0 = whi + (size_t)(h0off + ln16) * NH;
  const unsigned short* bl0 = wlo + (size_t)(h0off + ln16) * NH;
#pragma unroll
  for (int kt = 0; kt < 8; ++kt) {
    bf16x8 Ah, Al;
#pragma unroll
    for (int half = 0; half < 2; ++half)
#pragma unroll
      for (int j = 0; j < 4; ++j) {
        const uint32_t w = A.q[2 * kt + half][j];
        Ah[half * 4 + j] = (short)(w >> 16);
        Al[half * 4 + j] = (short)(w & 0xFFFFu);
      }
    const int ko = kt * 32 + lg * 8;
#pragma unroll
    for (int g = 0; g < 4; ++g) {
      const bf16x8 Bh = *(const bf16x8*)(bh0 + (size_t)g * (NH * NH) + ko);
      const bf16x8 Bl = *(const bf16x8*)(bl0 + (size_t)g * (NH * NH) + ko);
      acc[g] = __builtin_amdgcn_mfma_f32_16x16x32_bf16(Ah, Bh, acc[g], 0, 0, 0);
      acc[g] = __builtin_amdgcn_mfma_f32_16x16x32_bf16(Ah, Bl, acc[g], 0, 0, 0);
      acc[g] = __builtin_amdgcn_mfma_f32_16x16x32_bf16(Al, Bh, acc[g], 0, 0, 0);
    }
  }
}

// ---------- coalesced h-tile store: LDS 64x16 transpose -> 16B coherent stores ----------
__device__ __forceinline__ void store_htile(uint32_t* __restrict__ hplane,
                                            const uint32_t pk[4],
                                            uint32_t (*tr)[65],
                                            int b0, int h0off, int tx,
                                            int wv, int lg, int ln16) {
  __syncthreads();   // previous tr consumers done
#pragma unroll
  for (int r = 0; r < 4; ++r) tr[ln16][wv * 16 + lg * 4 + r] = pk[r];
  __syncthreads();
  const int ri = tx >> 2, c0 = (tx & 3) * 4;
  u32v4 v;
  v[0] = tr[c0 + 0][ri]; v[1] = tr[c0 + 1][ri];
  v[2] = tr[c0 + 2][ri]; v[3] = tr[c0 + 3][ri];
  uint32_t* dst = hplane + (size_t)(b0 + ri) * NH + h0off + c0;
  asm volatile("global_store_dwordx4 %0, %1, off sc0 sc1" :: "v"(dst), "v"(v) : "memory");
}

// ---------- split-phase group barrier: per-group monotonic counter ----------
// r8-proven mechanism; poll is now a BUSY SPIN (no s_sleep) to keep the issue
// pipes active so DPM holds clocks up during waits.
__device__ __forceinline__ void barrier_arrive(unsigned* ctr_line, unsigned* bno, int tx) {
  asm volatile("s_waitcnt vmcnt(0)" ::: "memory");  // sc stores LLC-acked
  __syncthreads();
  if (tx == 0)
    __hip_atomic_fetch_add(ctr_line, 1u, __ATOMIC_RELAXED, __HIP_MEMORY_SCOPE_AGENT);
  ++(*bno);
}
__device__ __forceinline__ void barrier_wait(unsigned* ctr_line, unsigned bno, int tx) {
  if (tx == 0) {
    while (__hip_atomic_load(ctr_line, __ATOMIC_RELAXED, __HIP_MEMORY_SCOPE_AGENT) <
           16u * bno) {
      // busy spin
    }
  }
  __syncthreads();
  asm volatile("" ::: "memory");
}

// ---------- the whole network in one launch ----------
__global__ __launch_bounds__(TPB, 1) void lstm_persist(
    const float* __restrict__ x,
    const float* __restrict__ eWih0, const float* __restrict__ eb0,
    const float* __restrict__ eb1,
    const float* __restrict__ dWih0, const float* __restrict__ db0,
    const float* __restrict__ db1,
    const float* __restrict__ fcW, const float* __restrict__ fcb,
    const unsigned short* __restrict__ wp,  // 12 planes
    uint32_t* __restrict__ hbase,           // 4 packed h planes
    unsigned* __restrict__ ctr,             // 16 groups x 32 u32 (1 line each)
    float* __restrict__ pred,               // [NHOR][NB]
    float* __restrict__ out) {
  __shared__ uint32_t tr[16][65];           // 4.2 KB transpose staging
  const int tx = threadIdx.x, bx = blockIdx.x;
  const int bt = bx & 15, ht = bx >> 4;
  const int b0 = bt * 64, h0off = ht * 16;
  const int wv = tx >> 6, l = tx & 63, lg = l >> 4, ln16 = l & 15;
  const int hcol = h0off + ln16;
  const int arow = b0 + wv * 16 + ln16;      // A-fragment row
  unsigned* ctr_line = &ctr[bt * 32];

  const unsigned short* W_eWhh0_hi = wp + 0 * 2 * PLANE;
  const unsigned short* W_eWhh0_lo = W_eWhh0_hi + PLANE;
  const unsigned short* W_eWih1_hi = wp + 1 * 2 * PLANE;
  const unsigned short* W_eWih1_lo = W_eWih1_hi + PLANE;
  const unsigned short* W_eWhh1_hi = wp + 2 * 2 * PLANE;
  const unsigned short* W_eWhh1_lo = W_eWhh1_hi + PLANE;
  const unsigned short* W_dWhh0_hi = wp + 3 * 2 * PLANE;
  const unsigned short* W_dWhh0_lo = W_dWhh0_hi + PLANE;
  const unsigned short* W_dWih1_hi = wp + 4 * 2 * PLANE;
  const unsigned short* W_dWih1_lo = W_dWih1_hi + PLANE;
  const unsigned short* W_dWhh1_hi = wp + 5 * 2 * PLANE;
  const unsigned short* W_dWhh1_lo = W_dWhh1_hi + PLANE;

  const int HP = NB * NH;
  uint32_t* h0c = hbase + 0 * HP; uint32_t* h0n = hbase + 1 * HP;
  uint32_t* h1c = hbase + 2 * HP; uint32_t* h1n = hbase + 3 * HP;

  // per-thread constants
  float ewv[4], eb0v[4], eb1v[4], dwv[4], db0v[4], db1v[4];
#pragma unroll
  for (int g = 0; g < 4; ++g) {
    ewv[g]  = eWih0[g * NH + hcol];
    eb0v[g] = eb0[g * NH + hcol];
    eb1v[g] = eb1[g * NH + hcol];
    dwv[g]  = dWih0[g * NH + hcol];
    db0v[g] = db0[g * NH + hcol];
    db1v[g] = db1[g * NH + hcol];
  }
  const float fcwv = fcW[hcol];
  const float fcbv = fcb[0];

  float c0r[4] = {0.f, 0.f, 0.f, 0.f};
  float c1r[4] = {0.f, 0.f, 0.f, 0.f};
  unsigned bno = 0;

  // ---- interval s=0: layer0(0) only (no gemm) ----
  {
    uint32_t pk[4];
#pragma unroll
    for (int r = 0; r < 4; ++r) {
      const int b = b0 + wv * 16 + lg * 4 + r;
      const float pv = x[b * NLOOK + 0];
      const float ig = sigm(pv * ewv[0] + eb0v[0]);
      const float fg = sigm(pv * ewv[1] + eb0v[1]);
      const float gg = tanh_(pv * ewv[2] + eb0v[2]);
      const float og = sigm(pv * ewv[3] + eb0v[3]);
      c0r[r] = fg * c0r[r] + ig * gg;
      pk[r] = pack_h(og * tanh_(c0r[r]));
    }
    store_htile(h0n, pk, tr, b0, h0off, tx, wv, lg, ln16);
    barrier_arrive(ctr_line, &bno, tx);
    { uint32_t* s0 = h0c; h0c = h0n; h0n = s0; }
  }

  // ---- fused encoder intervals s=1..336: layer1(s-1) + layer0(s) ----
  // A0 AND A1 both loaded POST-wait (r10's fix for r8's provable pre-wait race
  // on other blocks' h1 tiles).
  for (int s = 1; s <= NLOOK; ++s) {
    float xv[4];
    if (s <= NLOOK - 1) {
#pragma unroll
      for (int r = 0; r < 4; ++r)
        xv[r] = x[(b0 + wv * 16 + lg * 4 + r) * NLOOK + s];
    }
    barrier_wait(ctr_line, bno, tx);   // publishes h0(s-1), h1(s-2)

    APlane A0, A1;
    aplane_issue(A0, h0c, arow, lg);   // h0(s-1), shared by both layers' gemms
    if (s >= 2) aplane_issue(A1, h1c, arow, lg);
    wait_vm0();

    // layer1(s-1)
    f32x4 acc1[4] = {};
    gemm_frag(acc1, A0, W_eWih1_hi, W_eWih1_lo, h0off, lg, ln16);
    if (s >= 2) gemm_frag(acc1, A1, W_eWhh1_hi, W_eWhh1_lo, h0off, lg, ln16);
    uint32_t pk1[4];
#pragma unroll
    for (int r = 0; r < 4; ++r) {
      const float ig = sigm(acc1[0][r] + eb1v[0]);
      const float fg = sigm(acc1[1][r] + eb1v[1]);
      const float gg = tanh_(acc1[2][r] + eb1v[2]);
      const float og = sigm(acc1[3][r] + eb1v[3]);
      c1r[r] = fg * c1r[r] + ig * gg;
      pk1[r] = pack_h(og * tanh_(c1r[r]));
    }
    store_htile(h1n, pk1, tr, b0, h0off, tx, wv, lg, ln16);

    // layer0(s)
    if (s <= NLOOK - 1) {
      f32x4 acc0[4] = {};
      gemm_frag(acc0, A0, W_eWhh0_hi, W_eWhh0_lo, h0off, lg, ln16);
      uint32_t pk0[4];
#pragma unroll
      for (int r = 0; r < 4; ++r) {
        const float ig = sigm(acc0[0][r] + xv[r] * ewv[0] + eb0v[0]);
        const float fg = sigm(acc0[1][r] + xv[r] * ewv[1] + eb0v[1]);
        const float gg = tanh_(acc0[2][r] + xv[r] * ewv[2] + eb0v[2]);
        const float og = sigm(acc0[3][r] + xv[r] * ewv[3] + eb0v[3]);
        c0r[r] = fg * c0r[r] + ig * gg;
        pk0[r] = pack_h(og * tanh_(c0r[r]));
      }
      store_htile(h0n, pk0, tr, b0, h0off, tx, wv, lg, ln16);
    }
    barrier_arrive(ctr_line, &bno, tx);
    if (s <= NLOOK - 1) { uint32_t* s0 = h0c; h0c = h0n; h0n = s0; }
    { uint32_t* s0 = h1c; h1c = h1n; h1n = s0; }
  }

  // ---- decoder: 2 intervals per step (pre-wait loads barrier-covered) ----
  for (int t = 0; t < NHOR; ++t) {
    // ---- d0: layer0(t) ----
    {
      APlane A0;
      aplane_issue(A0, h0c, arow, lg);      // h0(t-1): covered by d1(t-1)'s wait
      float pvx[4];
      if (t == 0) {
#pragma unroll
        for (int r = 0; r < 4; ++r)
          pvx[r] = x[(b0 + wv * 16 + lg * 4 + r) * NLOOK + (NLOOK - 1)];
      }
      barrier_wait(ctr_line, bno, tx);      // publishes pred[t-1]
      wait_vm0();

      float pv[4];
#pragma unroll
      for (int r = 0; r < 4; ++r) {
        const int b = b0 + wv * 16 + lg * 4 + r;
        pv[r] = (t == 0) ? pvx[r]
                         : __hip_atomic_load(&pred[(t - 1) * NB + b],
                                             __ATOMIC_RELAXED, __HIP_MEMORY_SCOPE_AGENT);
      }
      f32x4 acc0[4] = {};
      gemm_frag(acc0, A0, W_dWhh0_hi, W_dWhh0_lo, h0off, lg, ln16);
      uint32_t pk0[4];
#pragma unroll
      for (int r = 0; r < 4; ++r) {
        const float ig = sigm(acc0[0][r] + pv[r] * dwv[0] + db0v[0]);
        const float fg = sigm(acc0[1][r] + pv[r] * dwv[1] + db0v[1]);
        const float gg = tanh_(acc0[2][r] + pv[r] * dwv[2] + db0v[2]);
        const float og = sigm(acc0[3][r] + pv[r] * dwv[3] + db0v[3]);
        c0r[r] = fg * c0r[r] + ig * gg;
        pk0[r] = pack_h(og * tanh_(c0r[r]));
      }
      store_htile(h0n, pk0, tr, b0, h0off, tx, wv, lg, ln16);
      if (ht == 0 && t >= 1 && ln16 == 0) {
#pragma unroll
        for (int r = 0; r < 4; ++r) {
          const int b = b0 + wv * 16 + lg * 4 + r;
          out[b * NHOR + (t - 1)] = pv[r];
        }
      }
      barrier_arrive(ctr_line, &bno, tx);
      { uint32_t* s0 = h0c; h0c = h0n; h0n = s0; }
    }

    // ---- d1: layer1(t) + fc ----
    {
      APlane A1;
      aplane_issue(A1, h1c, arow, lg);      // h1(t-1): covered by d0(t)'s wait
      barrier_wait(ctr_line, bno, tx);      // publishes h0(t)

      APlane A0;
      aplane_issue(A0, h0c, arow, lg);      // h0(t)
      wait_vm0();

      f32x4 acc1[4] = {};
      gemm_frag(acc1, A0, W_dWih1_hi, W_dWih1_lo, h0off, lg, ln16);
      gemm_frag(acc1, A1, W_dWhh1_hi, W_dWhh1_lo, h0off, lg, ln16);
      float hvr[4];
      uint32_t pk1[4];
#pragma unroll
      for (int r = 0; r < 4; ++r) {
        const float ig = sigm(acc1[0][r] + db1v[0]);
        const float fg = sigm(acc1[1][r] + db1v[1]);
        const float gg = tanh_(acc1[2][r] + db1v[2]);
        const float og = sigm(acc1[3][r] + db1v[3]);
        c1r[r] = fg * c1r[r] + ig * gg;
        hvr[r] = og * tanh_(c1r[r]);
        pk1[r] = pack_h(hvr[r]);
      }
      store_htile(h1n, pk1, tr, b0, h0off, tx, wv, lg, ln16);

      float s4[4];
#pragma unroll
      for (int r = 0; r < 4; ++r) s4[r] = hvr[r] * fcwv;
#pragma unroll
      for (int m = 1; m < 16; m <<= 1) {
#pragma unroll
        for (int r = 0; r < 4; ++r) s4[r] += __shfl_xor(s4[r], m, 64);
      }
      if (ln16 == 0) {
#pragma unroll
        for (int r = 0; r < 4; ++r) {
          const int b = b0 + wv * 16 + lg * 4 + r;
          float v = s4[r];
          if (ht == 0) v += fcbv;
          atomicAdd(&pred[t * NB + b], v);
        }
      }
      barrier_arrive(ctr_line, &bno, tx);
      { uint32_t* s0 = h1c; h1c = h1n; h1n = s0; }
    }
  }

  // ---- tail: publish final column ----
  barrier_wait(ctr_line, bno, tx);          // publishes pred[167]
  if (ht == 0 && ln16 == 0) {
#pragma unroll
    for (int r = 0; r < 4; ++r) {
      const int b = b0 + wv * 16 + lg * 4 + r;
      out[b * NHOR + (NHOR - 1)] =
          __hip_atomic_load(&pred[(NHOR - 1) * NB + b],
                            __ATOMIC_RELAXED, __HIP_MEMORY_SCOPE_AGENT);
    }
  }
}

extern "C" void kernel_launch(void* const* d_in, const int* in_sizes, int n_in,
                              void* d_out, int out_size, void* d_ws, size_t ws_size,
                              hipStream_t stream) {
  (void)in_sizes; (void)n_in; (void)out_size; (void)ws_size;
  const float* x     = (const float*)d_in[0];
  const float* eWih0 = (const float*)d_in[1];
  const float* eWhh0 = (const float*)d_in[2];
  const float* eb0   = (const float*)d_in[3];
  const float* eWih1 = (const float*)d_in[4];
  const float* eWhh1 = (const float*)d_in[5];
  const float* eb1   = (const float*)d_in[6];
  const float* dWih0 = (const float*)d_in[7];
  const float* dWhh0 = (const float*)d_in[8];
  const float* db0   = (const float*)d_in[9];
  const float* dWih1 = (const float*)d_in[10];
  const float* dWhh1 = (const float*)d_in[11];
  const float* db1   = (const float*)d_in[12];
  const float* fcW   = (const float*)d_in[13];
  const float* fcb   = (const float*)d_in[14];
  float* out = (float*)d_out;

  uint8_t* wsb = (uint8_t*)d_ws;
  unsigned* ctr = (unsigned*)wsb;                              // 16 groups x 128B
  float* pred = (float*)(wsb + 16384);                         // NHOR*NB*4
  unsigned short* wp = (unsigned short*)(wsb + 1048576);       // 12 planes = 6 MiB
  uint32_t* hbase = (uint32_t*)(wsb + 1048576 + (size_t)12 * PLANE * 2);  // 4 MiB

  hipMemsetAsync(d_ws, 0, 16384 + (size_t)NHOR * NB * 4, stream);

  const float* Wsrc[6] = { eWhh0, eWih1, eWhh1, dWhh0, dWih1, dWhh1 };
  for (int m = 0; m < 6; ++m)
    split_w<<<dim3(PLANE / TPB), dim3(TPB), 0, stream>>>(
        Wsrc[m], wp + (size_t)m * 2 * PLANE, wp + (size_t)m * 2 * PLANE + PLANE);

  lstm_persist<<<dim3(256), dim3(TPB), 0, stream>>>(
      x, eWih0, eb0, eb1, dWih0, db0, db1, fcW, fcb,
      wp, hbase, ctr, pred, out);
}